// Round 1
// baseline (47.399 us; speedup 1.0000x reference)
//
#include <hip/hip_runtime.h>

#define F_IN    32768
#define HID     64
#define NB_OBJ  16
#define BATCH   64
#define N_AGENTS 4
#define N_ACT   13
#define NEG_SLOPE 0.01f

#define FC      64               // f-chunk width per block
#define NCHUNK  (F_IN / FC)      // 512 split-K partials

// static scratch: 512 * 64 * 64 f32 = 8 MiB. Avoids relying on ws_size.
__device__ float g_part[NCHUNK * BATCH * HID];

// K1: fused node-mean + partial GEMM over one f-chunk, all 64 batches.
// grid = NCHUNK, block = 256 (4 waves).
__global__ __launch_bounds__(256, 2)
void k_gcn_partial(const float* __restrict__ u, const float* __restrict__ w) {
    __shared__ float xbar[BATCH][FC + 4];   // pad row to 68 floats (bank spread)
    const int t    = threadIdx.x;
    const int blk  = blockIdx.x;
    const int f0   = blk * FC;
    const int lane = t & 63;
    const int wv   = t >> 6;

    // prefetch this chunk's w column slice into registers:
    // wreg[f] = w[(f0+f)*HID + lane]  (lane == output h). Coalesced 256B/instr.
    float wreg[FC];
    {
        const float* wp = w + (size_t)f0 * HID + lane;
        #pragma unroll
        for (int f = 0; f < FC; ++f) wreg[f] = wp[f * HID];
    }

    // step A: xbar[b][f] = (1/16) * sum_o u[b][o][f0+f]
    // thread (b = t>>2, j = t&3) owns f-quads {j, j+4, j+8, j+12}
    {
        const int b = t >> 2;
        const int j = t & 3;
        const float* up = u + (size_t)b * (NB_OBJ * F_IN) + f0 + j * 4;
        float4 acc[4];
        #pragma unroll
        for (int q = 0; q < 4; ++q) acc[q] = make_float4(0.f, 0.f, 0.f, 0.f);
        #pragma unroll
        for (int o = 0; o < NB_OBJ; ++o) {
            const float* ro = up + o * F_IN;
            #pragma unroll
            for (int q = 0; q < 4; ++q) {
                float4 v = *reinterpret_cast<const float4*>(ro + q * 16);
                acc[q].x += v.x; acc[q].y += v.y;
                acc[q].z += v.z; acc[q].w += v.w;
            }
        }
        const float inv = 1.0f / (float)NB_OBJ;
        #pragma unroll
        for (int q = 0; q < 4; ++q) {
            float4 s = make_float4(acc[q].x * inv, acc[q].y * inv,
                                   acc[q].z * inv, acc[q].w * inv);
            *reinterpret_cast<float4*>(&xbar[b][(j + 4 * q) * 4]) = s;
        }
    }
    __syncthreads();

    // step B: each wave computes partials for 16 batches, lane = output h.
    // xbar reads are wave-broadcast (same addr all lanes) -> conflict-free.
    {
        float* pout = g_part + (size_t)blk * (BATCH * HID) + lane;
        for (int b16 = 0; b16 < 16; ++b16) {
            const int b = wv * 16 + b16;
            float acc = 0.f;
            #pragma unroll
            for (int fq = 0; fq < FC / 4; ++fq) {
                float4 xb = *reinterpret_cast<const float4*>(&xbar[b][fq * 4]);
                acc += xb.x * wreg[fq * 4 + 0];
                acc += xb.y * wreg[fq * 4 + 1];
                acc += xb.z * wreg[fq * 4 + 2];
                acc += xb.w * wreg[fq * 4 + 3];
            }
            pout[b * HID] = acc;
        }
    }
}

// K2: reduce split-K partials -> pooled, then per-agent heads + argmax gather.
// grid = BATCH, block = 256.
__global__ __launch_bounds__(256)
void k_heads(const float* __restrict__ gcn_b,
             const float* __restrict__ w1, const float* __restrict__ b1,
             const float* __restrict__ w2, const float* __restrict__ b2,
             const float* __restrict__ actions, float* __restrict__ out) {
    const int b = blockIdx.x;
    const int t = threadIdx.x;
    __shared__ float red[4][HID];
    __shared__ float pooled[HID];
    __shared__ float zbuf[N_AGENTS][HID];
    __shared__ float qbuf[N_AGENTS][N_ACT];

    // phase 1: pooled[h] = sum_k part[k][b][h] + gcn_b[h]
    {
        const int h = t & 63, s = t >> 6;
        const float* p = g_part + (size_t)s * (NCHUNK / 4) * (BATCH * HID)
                       + (size_t)b * HID + h;
        float acc = 0.f;
        for (int k = 0; k < NCHUNK / 4; ++k)
            acc += p[(size_t)k * (BATCH * HID)];
        red[s][h] = acc;
    }
    __syncthreads();
    if (t < HID)
        pooled[t] = red[0][t] + red[1][t] + red[2][t] + red[3][t] + gcn_b[t];
    __syncthreads();

    // phase 2: z[a][k] = leaky(b1 + sum_h pooled[h] * w1[a][h][k])
    {
        const int a = t >> 6, k = t & 63;
        const float* w1p = w1 + a * (HID * HID) + k;
        float acc = b1[a * HID + k];
        #pragma unroll
        for (int hh = 0; hh < HID; ++hh) acc += pooled[hh] * w1p[hh * HID];
        zbuf[a][k] = (acc >= 0.f) ? acc : NEG_SLOPE * acc;
    }
    __syncthreads();

    // phase 3: q[a][c] = b2 + sum_h z[a][h] * w2[a][h][c]
    if (t < N_AGENTS * N_ACT) {
        const int a = t / N_ACT, c = t % N_ACT;
        const float* w2p = w2 + a * (HID * N_ACT) + c;
        float acc = b2[a * N_ACT + c];
        #pragma unroll
        for (int hh = 0; hh < HID; ++hh) acc += zbuf[a][hh] * w2p[hh * N_ACT];
        qbuf[a][c] = acc;
    }
    __syncthreads();

    // phase 4: argmax over actions (first max, matching jnp.argmax), gather
    if (t < N_AGENTS) {
        const float* ap = actions + ((size_t)t * BATCH + b) * N_ACT;
        int best = 0; float bv = ap[0];
        for (int c = 1; c < N_ACT; ++c) {
            float v = ap[c];
            if (v > bv) { bv = v; best = c; }
        }
        out[t * BATCH + b] = qbuf[t][best];
    }
}

extern "C" void kernel_launch(void* const* d_in, const int* in_sizes, int n_in,
                              void* d_out, int out_size, void* d_ws, size_t ws_size,
                              hipStream_t stream) {
    const float* u   = (const float*)d_in[0];
    // d_in[1] = binary_tensor: unused by the reference computation
    const float* act = (const float*)d_in[2];
    const float* gw  = (const float*)d_in[3];
    const float* gb  = (const float*)d_in[4];
    const float* w1  = (const float*)d_in[5];
    const float* b1  = (const float*)d_in[6];
    const float* w2  = (const float*)d_in[7];
    const float* b2  = (const float*)d_in[8];
    float* out = (float*)d_out;

    hipLaunchKernelGGL(k_gcn_partial, dim3(NCHUNK), dim3(256), 0, stream, u, gw);
    hipLaunchKernelGGL(k_heads, dim3(BATCH), dim3(256), 0, stream,
                       gb, w1, b1, w2, b2, act, out);
}

// Round 3
// 39.491 us; speedup vs baseline: 1.2002x; 1.2002x over previous
//
#include <hip/hip_runtime.h>

#define F_IN    32768
#define HID     64
#define NB_OBJ  16
#define BATCH   64
#define N_AGENTS 4
#define N_ACT   13
#define NEG_SLOPE 0.01f

#define FC      64               // f-chunk width per block
#define NCHUNK  (F_IN / FC)      // 512 split-K partials

typedef float f32x4 __attribute__((ext_vector_type(4)));  // native vec for builtins

// static scratch (avoids ws_size dependence):
// g_part  [NCHUNK][BATCH][HID]  = 8 MiB
// g_part2 [4][BATCH][HID]       = 64 KiB
__device__ float g_part[NCHUNK * BATCH * HID];
__device__ float g_part2[4 * BATCH * HID];

// ---------------------------------------------------------------------------
// K1: fused node-mean + partial GEMM over one 64-wide f-chunk, all 64 batches.
// grid = NCHUNK (512), block = 512 (8 waves) -> 2 blocks/CU, 16 waves/CU.
// ---------------------------------------------------------------------------
__global__ __launch_bounds__(512, 4)
void k_gcn_partial(const float* __restrict__ u, const float* __restrict__ w) {
    __shared__ float xbar[BATCH][FC + 4];   // row pitch 68 floats
    const int t    = threadIdx.x;
    const int blk  = blockIdx.x;
    const int f0   = blk * FC;
    const int lane = t & 63;
    const int wv   = t >> 6;                // 0..7

    // w column slice in registers: wreg[f] = w[(f0+f)*HID + lane]
    float wreg[FC];
    {
        const float* wp = w + (size_t)f0 * HID + lane;
        #pragma unroll
        for (int f = 0; f < FC; ++f) wreg[f] = wp[f * HID];
    }

    // step A: xbar[b][f] = (1/16) * sum_o u[b][o][f0+f]
    // thread (b = t>>3, j = t&7) owns float4s at f-offsets j*4 and 32+j*4.
    // Per-instruction wave pattern: 8 batches x 128 B contiguous segments.
    {
        const int b = t >> 3;
        const int j = t & 7;
        const float* up = u + (size_t)b * (NB_OBJ * F_IN) + f0 + j * 4;
        f32x4 a0 = (f32x4)(0.f);
        f32x4 a1 = (f32x4)(0.f);
        #pragma unroll
        for (int o = 0; o < NB_OBJ; ++o) {
            const float* ro = up + o * F_IN;
            f32x4 v0 = __builtin_nontemporal_load(reinterpret_cast<const f32x4*>(ro));
            f32x4 v1 = __builtin_nontemporal_load(reinterpret_cast<const f32x4*>(ro + 32));
            a0 += v0;
            a1 += v1;
        }
        const float inv = 1.0f / (float)NB_OBJ;
        a0 *= inv;
        a1 *= inv;
        *reinterpret_cast<f32x4*>(&xbar[b][j * 4])      = a0;
        *reinterpret_cast<f32x4*>(&xbar[b][32 + j * 4]) = a1;
    }
    __syncthreads();

    // step B: each wave computes partials for 8 batches; lane = output h.
    // xbar reads are wave-broadcast (same addr on all lanes) -> conflict-free.
    {
        float* pout = g_part + (size_t)blk * (BATCH * HID) + lane;
        #pragma unroll
        for (int bb = 0; bb < 8; ++bb) {
            const int b = wv * 8 + bb;
            float acc = 0.f;
            #pragma unroll
            for (int fq = 0; fq < FC / 4; ++fq) {
                f32x4 xb = *reinterpret_cast<const f32x4*>(&xbar[b][fq * 4]);
                acc += xb.x * wreg[fq * 4 + 0];
                acc += xb.y * wreg[fq * 4 + 1];
                acc += xb.z * wreg[fq * 4 + 2];
                acc += xb.w * wreg[fq * 4 + 3];
            }
            pout[b * HID] = acc;
        }
    }
}

// ---------------------------------------------------------------------------
// K2: reduce 512 partials -> 4 per (b,h), full-machine parallelism.
// grid = 256 (q = bid>>6 in 0..3, b = bid&63), block = 256.
// ---------------------------------------------------------------------------
__global__ __launch_bounds__(256)
void k_reduce() {
    __shared__ float red[4][HID];
    const int bid = blockIdx.x;
    const int q   = bid >> 6;
    const int b   = bid & 63;
    const int t   = threadIdx.x;
    const int h   = t & 63;
    const int kg  = t >> 6;   // 0..3

    // sum 32 chunks: k = q*128 + kg*32 + i. Per-instruction: 256 B coalesced.
    const float* p = g_part + ((size_t)(q * 128 + kg * 32)) * (BATCH * HID)
                   + (size_t)b * HID + h;
    float acc = 0.f;
    #pragma unroll 8
    for (int i = 0; i < 32; ++i)
        acc += p[(size_t)i * (BATCH * HID)];
    red[kg][h] = acc;
    __syncthreads();

    if (t < HID)
        g_part2[((size_t)q * BATCH + b) * HID + t] =
            red[0][t] + red[1][t] + red[2][t] + red[3][t];
}

// ---------------------------------------------------------------------------
// K3: finish pooled + per-agent heads + argmax gather. grid = BATCH, block 256.
// ---------------------------------------------------------------------------
__global__ __launch_bounds__(256)
void k_heads(const float* __restrict__ gcn_b,
             const float* __restrict__ w1, const float* __restrict__ b1,
             const float* __restrict__ w2, const float* __restrict__ b2,
             const float* __restrict__ actions, float* __restrict__ out) {
    const int b = blockIdx.x;
    const int t = threadIdx.x;
    __shared__ float pooled[HID];
    __shared__ float zbuf[N_AGENTS][HID];
    __shared__ float qbuf[N_AGENTS][N_ACT];

    if (t < HID) {
        float acc = gcn_b[t];
        #pragma unroll
        for (int q = 0; q < 4; ++q)
            acc += g_part2[((size_t)q * BATCH + b) * HID + t];
        pooled[t] = acc;
    }
    __syncthreads();

    // z[a][k] = leaky(b1 + sum_h pooled[h] * w1[a][h][k])
    {
        const int a = t >> 6, k = t & 63;
        const float* w1p = w1 + a * (HID * HID) + k;
        float acc = b1[a * HID + k];
        #pragma unroll
        for (int hh = 0; hh < HID; ++hh) acc += pooled[hh] * w1p[hh * HID];
        zbuf[a][k] = (acc >= 0.f) ? acc : NEG_SLOPE * acc;
    }
    __syncthreads();

    // q[a][c] = b2 + sum_h z[a][h] * w2[a][h][c]
    if (t < N_AGENTS * N_ACT) {
        const int a = t / N_ACT, c = t % N_ACT;
        const float* w2p = w2 + a * (HID * N_ACT) + c;
        float acc = b2[a * N_ACT + c];
        #pragma unroll
        for (int hh = 0; hh < HID; ++hh) acc += zbuf[a][hh] * w2p[hh * N_ACT];
        qbuf[a][c] = acc;
    }
    __syncthreads();

    // argmax over actions (first-max semantics, matching jnp.argmax), gather
    if (t < N_AGENTS) {
        const float* ap = actions + ((size_t)t * BATCH + b) * N_ACT;
        int best = 0; float bv = ap[0];
        for (int c = 1; c < N_ACT; ++c) {
            float v = ap[c];
            if (v > bv) { bv = v; best = c; }
        }
        out[t * BATCH + b] = qbuf[t][best];
    }
}

extern "C" void kernel_launch(void* const* d_in, const int* in_sizes, int n_in,
                              void* d_out, int out_size, void* d_ws, size_t ws_size,
                              hipStream_t stream) {
    const float* u   = (const float*)d_in[0];
    // d_in[1] = binary_tensor: dead in the reference computation
    const float* act = (const float*)d_in[2];
    const float* gw  = (const float*)d_in[3];
    const float* gb  = (const float*)d_in[4];
    const float* w1  = (const float*)d_in[5];
    const float* b1  = (const float*)d_in[6];
    const float* w2  = (const float*)d_in[7];
    const float* b2  = (const float*)d_in[8];
    float* out = (float*)d_out;

    hipLaunchKernelGGL(k_gcn_partial, dim3(NCHUNK), dim3(512), 0, stream, u, gw);
    hipLaunchKernelGGL(k_reduce,      dim3(256),    dim3(256), 0, stream);
    hipLaunchKernelGGL(k_heads,       dim3(BATCH),  dim3(256), 0, stream,
                       gb, w1, b1, w2, b2, act, out);
}